// Round 21
// baseline (209.865 us; speedup 1.0000x reference)
//
#include <hip/hip_runtime.h>
#include <hip/hip_bf16.h>

#define D 128        // EMBED == LAYER == 128
#define BSHIFT 6     // 64 users per bucket
#define BUSERS (1 << BSHIFT)
#define NBLK 256     // blocks for hist/scatter passes
#define CHUNK 1280   // edges staged per bucket-chunk (avg bucket ~1024)
#define MROWS 64     // pw: item rows per block

typedef __attribute__((ext_vector_type(8))) short bf16x8;
typedef __attribute__((ext_vector_type(4))) float f32x4;
typedef _Float16 f16x2 __attribute__((ext_vector_type(2)));

// round-to-nearest f32 -> bf16 bits
__device__ __forceinline__ unsigned int bf16rn(float f) {
  unsigned int u = __float_as_uint(f);
  return (u + 0x7fffu + ((u >> 16) & 1u)) >> 16;
}
// f32 -> fp16 bits (RNE via hardware cvt)
__device__ __forceinline__ unsigned short fp16rn(float f) {
  _Float16 h = (_Float16)f;
  return *reinterpret_cast<unsigned short*>(&h);
}

// ---------------------------------------------------------------------------
// pw tile body (device fn): P[m0:m0+64] = emb @ W, MFMA bf16, FP16 output.
// Wt (32 KB LDS) staged cooperatively; A-fragments direct from global.
// ---------------------------------------------------------------------------
__device__ __forceinline__ void pw_tile(
    const float* __restrict__ emb, const float* __restrict__ W,
    unsigned short* __restrict__ Ph, int n_items, int tile,
    unsigned short* Wt /* 128*128 shorts, swizzled */) {
  const int tid = threadIdx.x;
  const int m0 = tile * MROWS;

  // stage W^T bf16 swizzled: Wt[c][k], boff = c*256 + ((2k)^((c&7)<<4))
  for (int i = tid; i < 128 * 128; i += 256) {
    const int k = i >> 7, c = i & 127;
    const unsigned short v = (unsigned short)bf16rn(W[i]);
    const int boff = c * 256 + ((2 * k) ^ ((c & 7) << 4));
    *reinterpret_cast<unsigned short*>(reinterpret_cast<char*>(Wt) + boff) = v;
  }

  const int w = tid >> 6;
  const int lane = tid & 63;
  const int lr = lane & 15;
  const int lg = lane >> 4;

  // A fragments direct from global: row gr, k = ks*32 + lg*8 + j
  bf16x8 a[4];
  const int gr = m0 + w * 16 + lr;
#pragma unroll
  for (int ks = 0; ks < 4; ++ks) {
    float4 f0 = {0.f, 0.f, 0.f, 0.f}, f1 = {0.f, 0.f, 0.f, 0.f};
    if (gr < n_items) {
      const float* p = emb + (size_t)gr * 128 + ks * 32 + lg * 8;
      f0 = *reinterpret_cast<const float4*>(p);
      f1 = *reinterpret_cast<const float4*>(p + 4);
    }
    bf16x8 av;
    av[0] = (short)bf16rn(f0.x); av[1] = (short)bf16rn(f0.y);
    av[2] = (short)bf16rn(f0.z); av[3] = (short)bf16rn(f0.w);
    av[4] = (short)bf16rn(f1.x); av[5] = (short)bf16rn(f1.y);
    av[6] = (short)bf16rn(f1.z); av[7] = (short)bf16rn(f1.w);
    a[ks] = av;
  }
  __syncthreads();  // Wt ready

  f32x4 acc[8];
#pragma unroll
  for (int cs = 0; cs < 8; ++cs) acc[cs] = {0.f, 0.f, 0.f, 0.f};

#pragma unroll
  for (int cs = 0; cs < 8; ++cs) {
    const int c = cs * 16 + lr;
#pragma unroll
    for (int ks = 0; ks < 4; ++ks) {
      const int boff = c * 256 + (((ks * 64) + lg * 16) ^ ((lr & 7) << 4));
      const bf16x8 b = *reinterpret_cast<const bf16x8*>(
          reinterpret_cast<const char*>(Wt) + boff);
      acc[cs] = __builtin_amdgcn_mfma_f32_16x16x32_bf16(a[ks], b, acc[cs],
                                                        0, 0, 0);
    }
  }

#pragma unroll
  for (int cs = 0; cs < 8; ++cs) {
    const int c = cs * 16 + lr;
#pragma unroll
    for (int reg = 0; reg < 4; ++reg) {
      const int r = m0 + w * 16 + lg * 4 + reg;
      if (r < n_items)
        Ph[(size_t)r * 128 + c] = fp16rn(acc[cs][reg]);
    }
  }
}

// ---------------------------------------------------------------------------
// Kernel 1 (fused): blocks [0, npw1) -> pw tiles; [npw1, npw1+NBLK) -> hist.
// First hist block also resets the scan done-counter (graph-replay-safe).
// ---------------------------------------------------------------------------
__global__ __launch_bounds__(256) void pw_hist_kernel(
    const float* __restrict__ emb, const float* __restrict__ W,
    unsigned short* __restrict__ Ph, int n_items, int npw1,
    const int* __restrict__ rows, int* __restrict__ bcount, int n_edges,
    int epb, int nbuck, int* __restrict__ done) {
  __shared__ __align__(16) char smem[32768];
  const int tid = threadIdx.x;

  if ((int)blockIdx.x < npw1) {
    pw_tile(emb, W, Ph, n_items, blockIdx.x, (unsigned short*)smem);
  } else {
    if ((int)blockIdx.x == npw1 && tid == 0) *done = 0;
    int* h = (int*)smem;
    const int hb = blockIdx.x - npw1;
    for (int b = tid; b < nbuck; b += 256) h[b] = 0;
    __syncthreads();
    const int e0 = hb * epb;
    const int e1 = (e0 + epb < n_edges) ? e0 + epb : n_edges;
    for (int e = e0 + tid; e < e1; e += 256)
      atomicAdd(&h[rows[e] >> BSHIFT], 1);
    __syncthreads();
    for (int b = tid; b < nbuck; b += 256)
      bcount[(size_t)b * NBLK + hb] = h[b];
  }
}

// ---------------------------------------------------------------------------
// Kernel 2a: block sums + (last block) scan of partials -> blockoff.
// Last-block-done pattern: fence + atomic ticket, no spinning.
// ---------------------------------------------------------------------------
__global__ __launch_bounds__(1024) void blocksum_kernel(
    const int* __restrict__ in, int* __restrict__ partials,
    int* __restrict__ blockoff, int* __restrict__ done, int n, int nb) {
  __shared__ int lds[1024];
  __shared__ int is_last;
  const int tid = threadIdx.x;
  const int i = blockIdx.x * 1024 + tid;
  lds[tid] = (i < n) ? in[i] : 0;
  __syncthreads();
  for (int s = 512; s > 0; s >>= 1) {
    if (tid < s) lds[tid] += lds[tid + s];
    __syncthreads();
  }
  if (tid == 0) partials[blockIdx.x] = lds[0];
  __threadfence();
  if (tid == 0) {
    const int t = atomicAdd(done, 1);
    is_last = (t == nb - 1);
  }
  __syncthreads();
  if (is_last) {
    __threadfence();  // acquire all partials
    const int x = (tid < nb) ? partials[tid] : 0;
    lds[tid] = x;
    __syncthreads();
    for (int s = 1; s < 1024; s <<= 1) {
      const int y = (tid >= s) ? lds[tid - s] : 0;
      __syncthreads();
      lds[tid] += y;
      __syncthreads();
    }
    if (tid < nb) blockoff[tid] = lds[tid] - x;
  }
}

__global__ __launch_bounds__(1024) void localscan_kernel(
    const int* __restrict__ in, const int* __restrict__ blockoff,
    int* __restrict__ base, int n) {
  __shared__ int lds[1024];
  const int tid = threadIdx.x;
  const int i = blockIdx.x * 1024 + tid;
  const int x = (i < n) ? in[i] : 0;
  lds[tid] = x;
  __syncthreads();
  for (int s = 1; s < 1024; s <<= 1) {
    const int y = (tid >= s) ? lds[tid - s] : 0;
    __syncthreads();
    lds[tid] += y;
    __syncthreads();
  }
  if (i < n) base[i] = blockoff[blockIdx.x] + lds[tid] - x;
}

// ---------------------------------------------------------------------------
// Kernel 3 (fused): blocks [0, NBLK) -> scatter; [NBLK, NBLK+npw2) -> pw.
// ---------------------------------------------------------------------------
__global__ __launch_bounds__(256) void scatter_pw_kernel(
    const int* __restrict__ rows, const int* __restrict__ cols,
    const float* __restrict__ vals, const int* __restrict__ base,
    int2* __restrict__ sedge, int n_edges, int epb, int nbuck,
    const float* __restrict__ emb, const float* __restrict__ W,
    unsigned short* __restrict__ Ph, int n_items, int npw1) {
  __shared__ __align__(16) char smem[32768];
  const int tid = threadIdx.x;

  if ((int)blockIdx.x >= NBLK) {
    pw_tile(emb, W, Ph, n_items, npw1 + (int)blockIdx.x - NBLK,
            (unsigned short*)smem);
    return;
  }
  int* cur = (int*)smem;
  for (int b = tid; b < nbuck; b += 256)
    cur[b] = base[(size_t)b * NBLK + blockIdx.x];
  __syncthreads();
  const int e0 = blockIdx.x * epb;
  const int e1 = (e0 + epb < n_edges) ? e0 + epb : n_edges;
  for (int e = e0 + tid; e < e1; e += 256) {
    const int r = rows[e];
    const int pos = atomicAdd(&cur[r >> BSHIFT], 1);
    sedge[pos] =
        make_int2(((r & (BUSERS - 1)) << 16) | cols[e], __float_as_int(vals[e]));
  }
}

// ---------------------------------------------------------------------------
// Kernel 4: per-bucket 64-key LDS counting-sort + lockstep quarter-wave
// accumulation with PACKED FP16 FMA (v_pk_fma_f16): ~6 VALU/edge/lane vs
// ~16 with bf16 unpack. Wave-uniform bounds (r18) keep 32 loads in flight.
// ---------------------------------------------------------------------------
__global__ __launch_bounds__(256) void bucket_gather_kernel(
    const uint4* __restrict__ Ph4,  // fp16, 16 uint4 per 256-B row
    const int* __restrict__ base, const int2* __restrict__ sedge,
    const float* __restrict__ nj, float* __restrict__ out, int n_users,
    int n_edges, int nbuck) {
  __shared__ int2 eraw[CHUNK];    // 10 KB
  __shared__ int2 esort[CHUNK];   // 10 KB
  __shared__ int cnt[BUSERS];
  __shared__ int incl[BUSERS];

  const int tid = threadIdx.x;
  const int b = blockIdx.x;
  const int u0 = b << BSHIFT;
  const int qw = tid >> 4;        // quarter-wave 0..15
  const int l16 = tid & 15;       // lane within quarter-wave

  const int beg = base[(size_t)b * NBLK];
  const int end = (b + 1 < nbuck) ? base[(size_t)(b + 1) * NBLK] : n_edges;

  f16x2 acc[4][4];                // 4 users x 4 fp16-pairs (8 cols)
#pragma unroll
  for (int k = 0; k < 4; ++k)
#pragma unroll
    for (int m = 0; m < 4; ++m) acc[k][m] = (f16x2){(_Float16)0, (_Float16)0};

  for (int cbeg = beg; cbeg < end; cbeg += CHUNK) {
    const int cnum = (cbeg + CHUNK < end) ? CHUNK : (end - cbeg);
    if (tid < BUSERS) cnt[tid] = 0;
    __syncthreads();
    for (int i = tid; i < cnum; i += 256) {
      const int2 e = sedge[cbeg + i];
      eraw[i] = e;
      atomicAdd(&cnt[((unsigned int)e.x) >> 16], 1);
    }
    __syncthreads();
    if (tid < BUSERS) incl[tid] = cnt[tid];
    __syncthreads();
    for (int s = 1; s < BUSERS; s <<= 1) {
      int y = 0;
      if (tid < BUSERS && tid >= s) y = incl[tid - s];
      __syncthreads();
      if (tid < BUSERS) incl[tid] += y;
      __syncthreads();
    }
    if (tid < BUSERS) cnt[tid] = incl[tid] - cnt[tid];
    __syncthreads();
    for (int i = tid; i < cnum; i += 256) {
      const int2 e = eraw[i];
      const int pos = atomicAdd(&cnt[((unsigned int)e.x) >> 16], 1);
      esort[pos] = e;
    }
    __syncthreads();

    // accumulate: lockstep groups, predicated edges, packed fp16 FMA
    if (cnum > 0) {
#pragma unroll
      for (int k = 0; k < 4; ++k) {
        const int ul = qw * 4 + k;
        const int s = (ul == 0) ? 0 : incl[ul - 1];
        const int t = incl[ul];
        // wave-uniform max segment length across this wave's 4 groups
        const int ub = ((qw >> 2) << 4) + k;   // wave*16 + k
        int wlen = 0;
#pragma unroll
        for (int m = 0; m < 4; ++m) {
          const int u2 = ub + m * 4;
          const int s2 = (u2 == 0) ? 0 : incl[u2 - 1];
          const int l2 = incl[u2] - s2;
          wlen = (l2 > wlen) ? l2 : wlen;
        }
        for (int i = 0; i < wlen; i += 8) {
          int2 e[8];
          uint4 p[8];
          _Float16 hv[8];
#pragma unroll
          for (int q = 0; q < 8; ++q) {
            const int j = s + i + q;
            const bool ok = (j < t);
            e[q] = esort[ok ? j : 0];
            hv[q] = (_Float16)(ok ? __int_as_float(e[q].y) : 0.f);
          }
#pragma unroll
          for (int q = 0; q < 8; ++q)
            p[q] = Ph4[(size_t)(e[q].x & 0xffff) * 16 + l16];
#pragma unroll
          for (int q = 0; q < 8; ++q) {
            const f16x2 vh = {hv[q], hv[q]};
            acc[k][0] = __builtin_elementwise_fma(
                vh, __builtin_bit_cast(f16x2, p[q].x), acc[k][0]);
            acc[k][1] = __builtin_elementwise_fma(
                vh, __builtin_bit_cast(f16x2, p[q].y), acc[k][1]);
            acc[k][2] = __builtin_elementwise_fma(
                vh, __builtin_bit_cast(f16x2, p[q].z), acc[k][2]);
            acc[k][3] = __builtin_elementwise_fma(
                vh, __builtin_bit_cast(f16x2, p[q].w), acc[k][3]);
          }
        }
      }
    }
    __syncthreads();  // protect LDS before next chunk
  }

  // epilogue: convert fp16 acc -> f32, scale by nj, two float4 stores
#pragma unroll
  for (int k = 0; k < 4; ++k) {
    const int u = u0 + qw * 4 + k;
    if (u < n_users) {
      const float s = nj[u];
      float4 a0, a1;
      a0.x = (float)acc[k][0][0] * s; a0.y = (float)acc[k][0][1] * s;
      a0.z = (float)acc[k][1][0] * s; a0.w = (float)acc[k][1][1] * s;
      a1.x = (float)acc[k][2][0] * s; a1.y = (float)acc[k][2][1] * s;
      a1.z = (float)acc[k][3][0] * s; a1.w = (float)acc[k][3][1] * s;
      float* o = out + (size_t)u * D + l16 * 8;
      *reinterpret_cast<float4*>(o) = a0;
      *reinterpret_cast<float4*>(o + 4) = a1;
    }
  }
}

extern "C" void kernel_launch(void* const* d_in, const int* in_sizes, int n_in,
                              void* d_out, int out_size, void* d_ws,
                              size_t ws_size, hipStream_t stream) {
  const float* item_emb = (const float*)d_in[0];  // [n_items, 128]
  const float* user_nj  = (const float*)d_in[1];  // [n_users, 1]
  const float* weight   = (const float*)d_in[2];  // [128, 128]
  const float* adj_vals = (const float*)d_in[3];  // [E]
  const int*   adj_rows = (const int*)d_in[4];    // [E]
  const int*   adj_cols = (const int*)d_in[5];    // [E]

  const int n_items = in_sizes[0] / D;
  const int n_users = in_sizes[1];
  const int n_edges = in_sizes[3];
  float* out = (float*)d_out;

  const int nbuck = (n_users + BUSERS - 1) >> BSHIFT;  // 1563
  const int npw = (n_items + MROWS - 1) / MROWS;       // 782
  const int npw1 = (npw + 1) / 2;                      // 391 (stage 1)
  const int npw2 = npw - npw1;                         // 391 (stage 3)
  const int epb = (n_edges + NBLK - 1) / NBLK;         // 6250
  const int n_scan = nbuck * NBLK;                     // 400128
  const int nb_scan = (n_scan + 1023) / 1024;          // 391

  // ---- workspace layout (256B-aligned) ----
  auto align256 = [](size_t x) { return (x + 255) & ~(size_t)255; };
  char* ws = (char*)d_ws;
  size_t off = 0;
  unsigned short* Ph = (unsigned short*)(ws + off);
  off = align256(off + (size_t)n_items * D * 2);  // 12.8 MB fp16
  int* bcount = (int*)(ws + off);  off = align256(off + (size_t)n_scan * 4);
  int* base = (int*)(ws + off);    off = align256(off + (size_t)n_scan * 4);
  int2* sedge = (int2*)(ws + off); off = align256(off + (size_t)n_edges * 8);
  int* partials = (int*)(ws + off); off = align256(off + (size_t)nb_scan * 4);
  int* blockoff = (int*)(ws + off); off = align256(off + (size_t)nb_scan * 4);
  int* done = (int*)(ws + off);     off = align256(off + 4);

  // 1) fused: pw tiles [0,npw1) || bucket histograms (+ done reset)
  pw_hist_kernel<<<npw1 + NBLK, 256, 0, stream>>>(
      item_emb, weight, Ph, n_items, npw1, adj_rows, bcount, n_edges, epb,
      nbuck, done);

  // 2) block sums (+ last-block scans partials), then local scan -> base
  blocksum_kernel<<<nb_scan, 1024, 0, stream>>>(bcount, partials, blockoff,
                                                done, n_scan, nb_scan);
  localscan_kernel<<<nb_scan, 1024, 0, stream>>>(bcount, blockoff, base,
                                                 n_scan);

  // 3) fused: scatter pass || pw tiles [npw1, npw)
  scatter_pw_kernel<<<NBLK + npw2, 256, 0, stream>>>(
      adj_rows, adj_cols, adj_vals, base, sedge, n_edges, epb, nbuck,
      item_emb, weight, Ph, n_items, npw1);

  // 4) per-bucket counting-sort + lockstep fp16-packed register gather
  bucket_gather_kernel<<<nbuck, 256, 0, stream>>>(
      reinterpret_cast<const uint4*>(Ph), base, sedge, user_nj, out,
      n_users, n_edges, nbuck);
}

// Round 23
// 113.394 us; speedup vs baseline: 1.8508x; 1.8508x over previous
//
#include <hip/hip_runtime.h>
#include <hip/hip_bf16.h>

#define D 128        // EMBED == LAYER == 128
#define BSHIFT 6     // 64 users per bucket
#define BUSERS (1 << BSHIFT)
#define NBLK 256     // blocks for hist/scatter passes
#define CHUNK 1280   // edges staged per bucket-chunk (avg bucket ~1024)
#define MROWS 64     // pw: item rows per block

typedef __attribute__((ext_vector_type(8))) short bf16x8;
typedef __attribute__((ext_vector_type(4))) float f32x4;
typedef _Float16 f16x2 __attribute__((ext_vector_type(2)));

// round-to-nearest f32 -> bf16 bits
__device__ __forceinline__ unsigned int bf16rn(float f) {
  unsigned int u = __float_as_uint(f);
  return (u + 0x7fffu + ((u >> 16) & 1u)) >> 16;
}
// f32 -> fp16 bits (RNE via hardware cvt)
__device__ __forceinline__ unsigned short fp16rn(float f) {
  _Float16 h = (_Float16)f;
  return *reinterpret_cast<unsigned short*>(&h);
}

// ---------------------------------------------------------------------------
// pw tile body (device fn): P[m0:m0+64] = emb @ W, MFMA bf16, FP16 output.
// Wt (32 KB LDS) staged cooperatively; A-fragments direct from global.
// ---------------------------------------------------------------------------
__device__ __forceinline__ void pw_tile(
    const float* __restrict__ emb, const float* __restrict__ W,
    unsigned short* __restrict__ Ph, int n_items, int tile,
    unsigned short* Wt /* 128*128 shorts, swizzled */) {
  const int tid = threadIdx.x;
  const int m0 = tile * MROWS;

  // stage W^T bf16 swizzled: Wt[c][k], boff = c*256 + ((2k)^((c&7)<<4))
  for (int i = tid; i < 128 * 128; i += 256) {
    const int k = i >> 7, c = i & 127;
    const unsigned short v = (unsigned short)bf16rn(W[i]);
    const int boff = c * 256 + ((2 * k) ^ ((c & 7) << 4));
    *reinterpret_cast<unsigned short*>(reinterpret_cast<char*>(Wt) + boff) = v;
  }

  const int w = tid >> 6;
  const int lane = tid & 63;
  const int lr = lane & 15;
  const int lg = lane >> 4;

  // A fragments direct from global: row gr, k = ks*32 + lg*8 + j
  bf16x8 a[4];
  const int gr = m0 + w * 16 + lr;
#pragma unroll
  for (int ks = 0; ks < 4; ++ks) {
    float4 f0 = {0.f, 0.f, 0.f, 0.f}, f1 = {0.f, 0.f, 0.f, 0.f};
    if (gr < n_items) {
      const float* p = emb + (size_t)gr * 128 + ks * 32 + lg * 8;
      f0 = *reinterpret_cast<const float4*>(p);
      f1 = *reinterpret_cast<const float4*>(p + 4);
    }
    bf16x8 av;
    av[0] = (short)bf16rn(f0.x); av[1] = (short)bf16rn(f0.y);
    av[2] = (short)bf16rn(f0.z); av[3] = (short)bf16rn(f0.w);
    av[4] = (short)bf16rn(f1.x); av[5] = (short)bf16rn(f1.y);
    av[6] = (short)bf16rn(f1.z); av[7] = (short)bf16rn(f1.w);
    a[ks] = av;
  }
  __syncthreads();  // Wt ready

  f32x4 acc[8];
#pragma unroll
  for (int cs = 0; cs < 8; ++cs) acc[cs] = {0.f, 0.f, 0.f, 0.f};

#pragma unroll
  for (int cs = 0; cs < 8; ++cs) {
    const int c = cs * 16 + lr;
#pragma unroll
    for (int ks = 0; ks < 4; ++ks) {
      const int boff = c * 256 + (((ks * 64) + lg * 16) ^ ((lr & 7) << 4));
      const bf16x8 b = *reinterpret_cast<const bf16x8*>(
          reinterpret_cast<const char*>(Wt) + boff);
      acc[cs] = __builtin_amdgcn_mfma_f32_16x16x32_bf16(a[ks], b, acc[cs],
                                                        0, 0, 0);
    }
  }

#pragma unroll
  for (int cs = 0; cs < 8; ++cs) {
    const int c = cs * 16 + lr;
#pragma unroll
    for (int reg = 0; reg < 4; ++reg) {
      const int r = m0 + w * 16 + lg * 4 + reg;
      if (r < n_items)
        Ph[(size_t)r * 128 + c] = fp16rn(acc[cs][reg]);
    }
  }
}

// ---------------------------------------------------------------------------
// Kernel 1 (fused): blocks [0, npw1) -> pw tiles; [npw1, npw1+NBLK) -> hist.
// ---------------------------------------------------------------------------
__global__ __launch_bounds__(256) void pw_hist_kernel(
    const float* __restrict__ emb, const float* __restrict__ W,
    unsigned short* __restrict__ Ph, int n_items, int npw1,
    const int* __restrict__ rows, int* __restrict__ bcount, int n_edges,
    int epb, int nbuck) {
  __shared__ __align__(16) char smem[32768];
  const int tid = threadIdx.x;

  if ((int)blockIdx.x < npw1) {
    pw_tile(emb, W, Ph, n_items, blockIdx.x, (unsigned short*)smem);
  } else {
    int* h = (int*)smem;
    const int hb = blockIdx.x - npw1;
    for (int b = tid; b < nbuck; b += 256) h[b] = 0;
    __syncthreads();
    const int e0 = hb * epb;
    const int e1 = (e0 + epb < n_edges) ? e0 + epb : n_edges;
    for (int e = e0 + tid; e < e1; e += 256)
      atomicAdd(&h[rows[e] >> BSHIFT], 1);
    __syncthreads();
    for (int b = tid; b < nbuck; b += 256)
      bcount[(size_t)b * NBLK + hb] = h[b];
  }
}

// ---------------------------------------------------------------------------
// 3-kernel exclusive scan over bcount (nbuck*NBLK entries) -> base.
// NO inter-block communication/fences — r21 measured __threadfence-based
// last-block-done at ~105 us (buffer_wbl2 per block); 3 launches cost ~3 us.
// ---------------------------------------------------------------------------
__global__ __launch_bounds__(1024) void blocksum_kernel(
    const int* __restrict__ in, int* __restrict__ partials, int n) {
  __shared__ int lds[1024];
  const int tid = threadIdx.x;
  const int i = blockIdx.x * 1024 + tid;
  lds[tid] = (i < n) ? in[i] : 0;
  __syncthreads();
  for (int s = 512; s > 0; s >>= 1) {
    if (tid < s) lds[tid] += lds[tid + s];
    __syncthreads();
  }
  if (tid == 0) partials[blockIdx.x] = lds[0];
}

__global__ __launch_bounds__(1024) void scanpart_kernel(
    const int* __restrict__ partials, int* __restrict__ blockoff, int nb) {
  __shared__ int lds[1024];
  const int tid = threadIdx.x;
  const int x = (tid < nb) ? partials[tid] : 0;
  lds[tid] = x;
  __syncthreads();
  for (int s = 1; s < 1024; s <<= 1) {
    const int y = (tid >= s) ? lds[tid - s] : 0;
    __syncthreads();
    lds[tid] += y;
    __syncthreads();
  }
  if (tid < nb) blockoff[tid] = lds[tid] - x;
}

__global__ __launch_bounds__(1024) void localscan_kernel(
    const int* __restrict__ in, const int* __restrict__ blockoff,
    int* __restrict__ base, int n) {
  __shared__ int lds[1024];
  const int tid = threadIdx.x;
  const int i = blockIdx.x * 1024 + tid;
  const int x = (i < n) ? in[i] : 0;
  lds[tid] = x;
  __syncthreads();
  for (int s = 1; s < 1024; s <<= 1) {
    const int y = (tid >= s) ? lds[tid - s] : 0;
    __syncthreads();
    lds[tid] += y;
    __syncthreads();
  }
  if (i < n) base[i] = blockoff[blockIdx.x] + lds[tid] - x;
}

// ---------------------------------------------------------------------------
// Kernel 3 (fused): blocks [0, NBLK) -> scatter; [NBLK, NBLK+npw2) -> pw.
// ---------------------------------------------------------------------------
__global__ __launch_bounds__(256) void scatter_pw_kernel(
    const int* __restrict__ rows, const int* __restrict__ cols,
    const float* __restrict__ vals, const int* __restrict__ base,
    int2* __restrict__ sedge, int n_edges, int epb, int nbuck,
    const float* __restrict__ emb, const float* __restrict__ W,
    unsigned short* __restrict__ Ph, int n_items, int npw1) {
  __shared__ __align__(16) char smem[32768];
  const int tid = threadIdx.x;

  if ((int)blockIdx.x >= NBLK) {
    pw_tile(emb, W, Ph, n_items, npw1 + (int)blockIdx.x - NBLK,
            (unsigned short*)smem);
    return;
  }
  int* cur = (int*)smem;
  for (int b = tid; b < nbuck; b += 256)
    cur[b] = base[(size_t)b * NBLK + blockIdx.x];
  __syncthreads();
  const int e0 = blockIdx.x * epb;
  const int e1 = (e0 + epb < n_edges) ? e0 + epb : n_edges;
  for (int e = e0 + tid; e < e1; e += 256) {
    const int r = rows[e];
    const int pos = atomicAdd(&cur[r >> BSHIFT], 1);
    sedge[pos] =
        make_int2(((r & (BUSERS - 1)) << 16) | cols[e], __float_as_int(vals[e]));
  }
}

// ---------------------------------------------------------------------------
// Kernel 4: per-bucket 64-key LDS counting-sort + lockstep quarter-wave
// accumulation with PACKED FP16 FMA. Wave-uniform bounds (r18) keep 32
// loads in flight per wave.
// ---------------------------------------------------------------------------
__global__ __launch_bounds__(256) void bucket_gather_kernel(
    const uint4* __restrict__ Ph4,  // fp16, 16 uint4 per 256-B row
    const int* __restrict__ base, const int2* __restrict__ sedge,
    const float* __restrict__ nj, float* __restrict__ out, int n_users,
    int n_edges, int nbuck) {
  __shared__ int2 eraw[CHUNK];    // 10 KB
  __shared__ int2 esort[CHUNK];   // 10 KB
  __shared__ int cnt[BUSERS];
  __shared__ int incl[BUSERS];

  const int tid = threadIdx.x;
  const int b = blockIdx.x;
  const int u0 = b << BSHIFT;
  const int qw = tid >> 4;        // quarter-wave 0..15
  const int l16 = tid & 15;       // lane within quarter-wave

  const int beg = base[(size_t)b * NBLK];
  const int end = (b + 1 < nbuck) ? base[(size_t)(b + 1) * NBLK] : n_edges;

  f16x2 acc[4][4];                // 4 users x 4 fp16-pairs (8 cols)
#pragma unroll
  for (int k = 0; k < 4; ++k)
#pragma unroll
    for (int m = 0; m < 4; ++m) acc[k][m] = (f16x2){(_Float16)0, (_Float16)0};

  for (int cbeg = beg; cbeg < end; cbeg += CHUNK) {
    const int cnum = (cbeg + CHUNK < end) ? CHUNK : (end - cbeg);
    if (tid < BUSERS) cnt[tid] = 0;
    __syncthreads();
    for (int i = tid; i < cnum; i += 256) {
      const int2 e = sedge[cbeg + i];
      eraw[i] = e;
      atomicAdd(&cnt[((unsigned int)e.x) >> 16], 1);
    }
    __syncthreads();
    if (tid < BUSERS) incl[tid] = cnt[tid];
    __syncthreads();
    for (int s = 1; s < BUSERS; s <<= 1) {
      int y = 0;
      if (tid < BUSERS && tid >= s) y = incl[tid - s];
      __syncthreads();
      if (tid < BUSERS) incl[tid] += y;
      __syncthreads();
    }
    if (tid < BUSERS) cnt[tid] = incl[tid] - cnt[tid];
    __syncthreads();
    for (int i = tid; i < cnum; i += 256) {
      const int2 e = eraw[i];
      const int pos = atomicAdd(&cnt[((unsigned int)e.x) >> 16], 1);
      esort[pos] = e;
    }
    __syncthreads();

    // accumulate: lockstep groups, predicated edges, packed fp16 FMA
    if (cnum > 0) {
#pragma unroll
      for (int k = 0; k < 4; ++k) {
        const int ul = qw * 4 + k;
        const int s = (ul == 0) ? 0 : incl[ul - 1];
        const int t = incl[ul];
        // wave-uniform max segment length across this wave's 4 groups
        const int ub = ((qw >> 2) << 4) + k;   // wave*16 + k
        int wlen = 0;
#pragma unroll
        for (int m = 0; m < 4; ++m) {
          const int u2 = ub + m * 4;
          const int s2 = (u2 == 0) ? 0 : incl[u2 - 1];
          const int l2 = incl[u2] - s2;
          wlen = (l2 > wlen) ? l2 : wlen;
        }
        for (int i = 0; i < wlen; i += 8) {
          int2 e[8];
          uint4 p[8];
          _Float16 hv[8];
#pragma unroll
          for (int q = 0; q < 8; ++q) {
            const int j = s + i + q;
            const bool ok = (j < t);
            e[q] = esort[ok ? j : 0];
            hv[q] = (_Float16)(ok ? __int_as_float(e[q].y) : 0.f);
          }
#pragma unroll
          for (int q = 0; q < 8; ++q)
            p[q] = Ph4[(size_t)(e[q].x & 0xffff) * 16 + l16];
#pragma unroll
          for (int q = 0; q < 8; ++q) {
            const f16x2 vh = {hv[q], hv[q]};
            acc[k][0] = __builtin_elementwise_fma(
                vh, __builtin_bit_cast(f16x2, p[q].x), acc[k][0]);
            acc[k][1] = __builtin_elementwise_fma(
                vh, __builtin_bit_cast(f16x2, p[q].y), acc[k][1]);
            acc[k][2] = __builtin_elementwise_fma(
                vh, __builtin_bit_cast(f16x2, p[q].z), acc[k][2]);
            acc[k][3] = __builtin_elementwise_fma(
                vh, __builtin_bit_cast(f16x2, p[q].w), acc[k][3]);
          }
        }
      }
    }
    __syncthreads();  // protect LDS before next chunk
  }

  // epilogue: convert fp16 acc -> f32, scale by nj, two float4 stores
#pragma unroll
  for (int k = 0; k < 4; ++k) {
    const int u = u0 + qw * 4 + k;
    if (u < n_users) {
      const float s = nj[u];
      float4 a0, a1;
      a0.x = (float)acc[k][0][0] * s; a0.y = (float)acc[k][0][1] * s;
      a0.z = (float)acc[k][1][0] * s; a0.w = (float)acc[k][1][1] * s;
      a1.x = (float)acc[k][2][0] * s; a1.y = (float)acc[k][2][1] * s;
      a1.z = (float)acc[k][3][0] * s; a1.w = (float)acc[k][3][1] * s;
      float* o = out + (size_t)u * D + l16 * 8;
      *reinterpret_cast<float4*>(o) = a0;
      *reinterpret_cast<float4*>(o + 4) = a1;
    }
  }
}

extern "C" void kernel_launch(void* const* d_in, const int* in_sizes, int n_in,
                              void* d_out, int out_size, void* d_ws,
                              size_t ws_size, hipStream_t stream) {
  const float* item_emb = (const float*)d_in[0];  // [n_items, 128]
  const float* user_nj  = (const float*)d_in[1];  // [n_users, 1]
  const float* weight   = (const float*)d_in[2];  // [128, 128]
  const float* adj_vals = (const float*)d_in[3];  // [E]
  const int*   adj_rows = (const int*)d_in[4];    // [E]
  const int*   adj_cols = (const int*)d_in[5];    // [E]

  const int n_items = in_sizes[0] / D;
  const int n_users = in_sizes[1];
  const int n_edges = in_sizes[3];
  float* out = (float*)d_out;

  const int nbuck = (n_users + BUSERS - 1) >> BSHIFT;  // 1563
  const int npw = (n_items + MROWS - 1) / MROWS;       // 782
  const int npw1 = (npw + 1) / 2;                      // 391 (stage 1)
  const int npw2 = npw - npw1;                         // 391 (stage 3)
  const int epb = (n_edges + NBLK - 1) / NBLK;         // 6250
  const int n_scan = nbuck * NBLK;                     // 400128
  const int nb_scan = (n_scan + 1023) / 1024;          // 391

  // ---- workspace layout (256B-aligned) ----
  auto align256 = [](size_t x) { return (x + 255) & ~(size_t)255; };
  char* ws = (char*)d_ws;
  size_t off = 0;
  unsigned short* Ph = (unsigned short*)(ws + off);
  off = align256(off + (size_t)n_items * D * 2);  // 12.8 MB fp16
  int* bcount = (int*)(ws + off);  off = align256(off + (size_t)n_scan * 4);
  int* base = (int*)(ws + off);    off = align256(off + (size_t)n_scan * 4);
  int2* sedge = (int2*)(ws + off); off = align256(off + (size_t)n_edges * 8);
  int* partials = (int*)(ws + off); off = align256(off + (size_t)nb_scan * 4);
  int* blockoff = (int*)(ws + off); off = align256(off + (size_t)nb_scan * 4);

  // 1) fused: pw tiles [0,npw1) || bucket histograms
  pw_hist_kernel<<<npw1 + NBLK, 256, 0, stream>>>(
      item_emb, weight, Ph, n_items, npw1, adj_rows, bcount, n_edges, epb,
      nbuck);

  // 2) 3-kernel exclusive scan of bcount -> base (no inter-block comms)
  blocksum_kernel<<<nb_scan, 1024, 0, stream>>>(bcount, partials, n_scan);
  scanpart_kernel<<<1, 1024, 0, stream>>>(partials, blockoff, nb_scan);
  localscan_kernel<<<nb_scan, 1024, 0, stream>>>(bcount, blockoff, base,
                                                 n_scan);

  // 3) fused: scatter pass || pw tiles [npw1, npw)
  scatter_pw_kernel<<<NBLK + npw2, 256, 0, stream>>>(
      adj_rows, adj_cols, adj_vals, base, sedge, n_edges, epb, nbuck,
      item_emb, weight, Ph, n_items, npw1);

  // 4) per-bucket counting-sort + lockstep fp16-packed register gather
  bucket_gather_kernel<<<nbuck, 256, 0, stream>>>(
      reinterpret_cast<const uint4*>(Ph), base, sedge, user_nj, out,
      n_users, n_edges, nbuck);
}